// Round 11
// baseline (325.675 us; speedup 1.0000x reference)
//
#include <hip/hip_runtime.h>
#include <hip/hip_cooperative_groups.h>
#include <math.h>

namespace cg = cooperative_groups;

#define GN 50000
#define GE 800000
#define INF 128
#define OUTF 64
#define LRELU_ALPHA 0.2f

#define BUCKW   49                          // dsts per bucket
#define NB      1021                        // ceil(50000/49)
#define CAP     1024                        // bucket capacity (mean 783, +8.6 sigma)
#define CHUNK   4096                        // edges per multisplit task
#define NCH     ((GE + CHUNK - 1) / CHUNK)  // 196
#define NGT     782                         // gemm tasks (64 nodes each)
#define NT1     (NGT + NCH)                 // 978 phase-1 tasks

// floor(d/49) for d < 50000 via magic mul (exact: proof in journal R11)
__device__ __forceinline__ unsigned div49(unsigned d) {
    return (d * 85599u) >> 22;
}

// ---- bf16 helpers (RNE pack, cheap unpack) --------------------------------
__device__ __forceinline__ unsigned short f32_to_bf16(float f) {
    unsigned int u = __float_as_uint(f);
    return (unsigned short)((u + 0x7fffu + ((u >> 16) & 1u)) >> 16);
}
__device__ __forceinline__ float bf16lo(unsigned int u) { return __uint_as_float(u << 16); }
__device__ __forceinline__ float bf16hi(unsigned int u) { return __uint_as_float(u & 0xffff0000u); }

// ---------------------------------------------------------------------------
// Single cooperative kernel:
//  phase 0: zero ccount                       -> grid.sync
//  phase 1: tasks [0,782): GEMM (64 nodes, 4/thread; W in LDS)
//           tasks [782,978): edge multisplit into fixed CAP bucket regions
//                                              -> grid.sync
//  phase 2: one bucket per block: LDS counting sort (49 bins) + softmax +
//           bf16 Wh gather (8-lane groups, 8 feats/lane, 8-deep unrolled
//           loads) + ELU + coalesced store.
// All phases grid-stride -> correct for any grid size.
// ---------------------------------------------------------------------------
__global__ __launch_bounds__(256, 4)
void k_all(const float* __restrict__ h,
           const float* __restrict__ W,
           const float* __restrict__ a,
           const int* __restrict__ src,
           const int* __restrict__ dst,
           unsigned short* __restrict__ Whb,
           float* __restrict__ s1,
           float* __restrict__ s2,
           int* __restrict__ ccount,
           int* __restrict__ epacked,
           float* __restrict__ out) {
    __shared__ __align__(16) unsigned char smem[32768];
    int t = threadIdx.x;
    int grid = gridDim.x;
    cg::grid_group gg = cg::this_grid();

    // ================= phase 0: zero bucket counts =================
    for (int i = blockIdx.x * 256 + t; i < NB; i += grid * 256) ccount[i] = 0;
    gg.sync();

    // ================= phase 1 =================
    for (int task = blockIdx.x; task < NT1; task += grid) {
        if (task < NGT) {
            // ---- GEMM: 64 nodes, 4 nodes/thread (R8 config) ----
            float* Wlds = (float*)smem;  // 32 KB
            for (int i = t * 4; i < INF * OUTF; i += 256 * 4)
                *(float4*)&Wlds[i] = *(const float4*)&W[i];
            __syncthreads();

            int fg = t & 15;
            int ng = t >> 4;
            int jg = fg * 4;
            int n0 = task * 64 + ng * 4;

            int m0 = n0 + 0 < GN ? n0 + 0 : GN - 1;
            int m1 = n0 + 1 < GN ? n0 + 1 : GN - 1;
            int m2 = n0 + 2 < GN ? n0 + 2 : GN - 1;
            int m3 = n0 + 3 < GN ? n0 + 3 : GN - 1;
            const float* h0 = &h[m0 * INF];
            const float* h1 = &h[m1 * INF];
            const float* h2 = &h[m2 * INF];
            const float* h3 = &h[m3 * INF];

            float4 acc0 = {0.f,0.f,0.f,0.f}, acc1 = acc0, acc2 = acc0, acc3 = acc0;
            for (int kc = 0; kc < INF; kc += 4) {
                float4 hv0 = *(const float4*)&h0[kc];
                float4 hv1 = *(const float4*)&h1[kc];
                float4 hv2 = *(const float4*)&h2[kc];
                float4 hv3 = *(const float4*)&h3[kc];
                #pragma unroll
                for (int kk = 0; kk < 4; ++kk) {
                    float4 wv = *(float4*)&Wlds[(kc + kk) * OUTF + jg];
                    float a0 = ((const float*)&hv0)[kk];
                    float a1v = ((const float*)&hv1)[kk];
                    float a2v = ((const float*)&hv2)[kk];
                    float a3 = ((const float*)&hv3)[kk];
                    acc0.x += a0 * wv.x; acc0.y += a0 * wv.y; acc0.z += a0 * wv.z; acc0.w += a0 * wv.w;
                    acc1.x += a1v * wv.x; acc1.y += a1v * wv.y; acc1.z += a1v * wv.z; acc1.w += a1v * wv.w;
                    acc2.x += a2v * wv.x; acc2.y += a2v * wv.y; acc2.z += a2v * wv.z; acc2.w += a2v * wv.w;
                    acc3.x += a3 * wv.x; acc3.y += a3 * wv.y; acc3.z += a3 * wv.z; acc3.w += a3 * wv.w;
                }
            }

            float4 accs[4] = {acc0, acc1, acc2, acc3};
            #pragma unroll
            for (int i = 0; i < 4; ++i) {
                if (n0 + i < GN) {
                    ushort4 p;
                    p.x = f32_to_bf16(accs[i].x); p.y = f32_to_bf16(accs[i].y);
                    p.z = f32_to_bf16(accs[i].z); p.w = f32_to_bf16(accs[i].w);
                    *(ushort4*)&Whb[(n0 + i) * OUTF + jg] = p;
                }
            }

            float4 va1 = *(const float4*)&a[jg];
            float4 va2 = *(const float4*)&a[OUTF + jg];
            float p1[4], p2[4];
            #pragma unroll
            for (int i = 0; i < 4; ++i) {
                p1[i] = accs[i].x * va1.x + accs[i].y * va1.y + accs[i].z * va1.z + accs[i].w * va1.w;
                p2[i] = accs[i].x * va2.x + accs[i].y * va2.y + accs[i].z * va2.z + accs[i].w * va2.w;
            }
            #pragma unroll
            for (int off = 8; off >= 1; off >>= 1) {
                #pragma unroll
                for (int i = 0; i < 4; ++i) {
                    p1[i] += __shfl_down(p1[i], off, 16);
                    p2[i] += __shfl_down(p2[i], off, 16);
                }
            }
            if (fg == 0) {
                #pragma unroll
                for (int i = 0; i < 4; ++i) {
                    if (n0 + i < GN) { s1[n0 + i] = p1[i]; s2[n0 + i] = p2[i]; }
                }
            }
        } else {
            // ---- multisplit: 4096-edge chunk into bucket regions ----
            int* hist = (int*)smem;          // NB ints
            int* run  = hist + NB;           // NB ints (8.2 KB total)
            for (int i = t; i < NB; i += 256) hist[i] = 0;
            __syncthreads();

            int base = (task - NGT) * CHUNK;
            int pk[CHUNK / 256];
            int bb[CHUNK / 256];
            #pragma unroll
            for (int i = 0; i < CHUNK / 256; ++i) {
                int e = base + i * 256 + t;
                if (e < GE) {
                    unsigned d = (unsigned)dst[e];
                    unsigned b = div49(d);
                    pk[i] = (src[e] << 6) | (int)(d - b * BUCKW);
                    bb[i] = (int)b;
                    atomicAdd(&hist[b], 1);
                } else {
                    bb[i] = -1;
                }
            }
            __syncthreads();
            for (int i = t; i < NB; i += 256) {
                int c = hist[i];
                if (c > 0) run[i] = i * CAP + atomicAdd(&ccount[i], c);
            }
            __syncthreads();
            #pragma unroll
            for (int i = 0; i < CHUNK / 256; ++i) {
                if (bb[i] >= 0) {
                    int pos = atomicAdd(&run[bb[i]], 1);
                    epacked[pos] = pk[i];
                }
            }
        }
        __syncthreads();   // protect LDS before next grid-stride task
    }
    __threadfence();       // belt-and-braces: publish epacked/Whb across XCDs
    gg.sync();

    // ================= phase 2: one bucket per block =================
    int* elds   = (int*)smem;        // 1024
    int* sorted = elds + CAP;        // 1024
    int* hist   = sorted + CAP;      // 64
    int* cur    = hist + 64;         // 64
    int* cstart = cur + 64;          // 66 (65 used)
    float* s2l  = (float*)(cstart + 66);  // 49

    for (int b = blockIdx.x; b < NB; b += grid) {
        int dstbase = b * BUCKW;
        int nd = GN - dstbase;
        if (nd < 0) nd = 0; if (nd > BUCKW) nd = BUCKW;

        int start = b * CAP;
        int cnt = ccount[b];
        if (cnt > CAP) cnt = CAP;    // statistically impossible; safety only

        if (t < 64) hist[t] = 0;
        if (t < BUCKW) s2l[t] = (t < nd) ? s2[dstbase + t] : 0.f;
        __syncthreads();
        for (int i = t; i < cnt; i += 256) {
            int pk = epacked[start + i];
            elds[i] = pk;
            atomicAdd(&hist[pk & 63], 1);
        }
        __syncthreads();
        if (t < 64) {                    // wave 0: inclusive scan of 64 bins
            int v = hist[t];
            int incl = v;
            #pragma unroll
            for (int off = 1; off < 64; off <<= 1) {
                int u = __shfl_up(incl, off, 64);
                if (t >= off) incl += u;
            }
            cstart[t + 1] = incl;
            cur[t] = incl - v;
            if (t == 0) cstart[0] = 0;
        }
        __syncthreads();
        for (int i = t; i < cnt; i += 256) {
            int pk = elds[i];
            int pos = atomicAdd(&cur[pk & 63], 1);
            sorted[pos] = pk;
        }
        __syncthreads();

        int grp  = t >> 3;               // 32 groups of 8 lanes
        int lane = t & 7;
        int jg   = lane * 8;             // 8 feats per lane
        for (int dl = grp; dl < BUCKW; dl += 32) {
            int c0 = cstart[dl], c1 = cstart[dl + 1];
            float acc[8] = {0.f,0.f,0.f,0.f,0.f,0.f,0.f,0.f};
            float den = 0.f;
            float s2n = s2l[dl];
            for (int cb = c0; cb < c1; cb += 8) {
                int my = cb + lane;
                float ex_l = 0.f; int s_l = 0;
                if (my < c1) {
                    int pk = sorted[my];
                    s_l = pk >> 6;
                    float x = s1[s_l] + s2n;
                    x = (x > 0.f) ? x : LRELU_ALPHA * x;
                    ex_l = __expf(x);
                }
                int m = c1 - cb; if (m > 8) m = 8;
                int   sj[8]; float exj[8];
                #pragma unroll
                for (int j = 0; j < 8; ++j) {
                    exj[j] = __shfl(ex_l, j, 8);
                    sj[j]  = __shfl(s_l,  j, 8);
                }
                uint4 wv[8];
                #pragma unroll
                for (int j = 0; j < 8; ++j)
                    if (j < m) wv[j] = *(const uint4*)&Whb[sj[j] * OUTF + jg];
                #pragma unroll
                for (int j = 0; j < 8; ++j) {
                    if (j < m) {
                        float ex = exj[j];
                        den += ex;
                        acc[0] += ex * bf16lo(wv[j].x); acc[1] += ex * bf16hi(wv[j].x);
                        acc[2] += ex * bf16lo(wv[j].y); acc[3] += ex * bf16hi(wv[j].y);
                        acc[4] += ex * bf16lo(wv[j].z); acc[5] += ex * bf16hi(wv[j].z);
                        acc[6] += ex * bf16lo(wv[j].w); acc[7] += ex * bf16hi(wv[j].w);
                    }
                }
            }
            if (dl < nd) {
                float inv = (c1 > c0) ? 1.f / den : 0.f;
                float o[8];
                #pragma unroll
                for (int j = 0; j < 8; ++j) {
                    float v = acc[j] * inv;
                    o[j] = (v > 0.f) ? v : expm1f(v);
                }
                float* op = &out[(dstbase + dl) * OUTF + jg];
                *(float4*)(op + 0) = make_float4(o[0], o[1], o[2], o[3]);
                *(float4*)(op + 4) = make_float4(o[4], o[5], o[6], o[7]);
            }
        }
        __syncthreads();   // protect LDS before next grid-stride bucket
    }
}

extern "C" void kernel_launch(void* const* d_in, const int* in_sizes, int n_in,
                              void* d_out, int out_size, void* d_ws, size_t ws_size,
                              hipStream_t stream) {
    const float* h  = (const float*)d_in[0];
    const int*   ei = (const int*)d_in[1];    // [2, E]: first E = src, next E = dst
    const float* W  = (const float*)d_in[2];
    const float* a  = (const float*)d_in[3];
    const int* src = ei;
    const int* dst = ei + GE;

    float* ws = (float*)d_ws;
    float* s1 = ws;                                          // N
    float* s2 = s1 + GN;                                     // N
    unsigned short* Whb = (unsigned short*)(s2 + GN);        // N*64 bf16
    int* epacked = (int*)(Whb + (size_t)GN * OUTF);          // NB*CAP
    int* ccount  = epacked + (size_t)NB * CAP;               // NB
    float* out = (float*)d_out;

    int occ = 0;
    hipOccupancyMaxActiveBlocksPerMultiprocessor(&occ, (const void*)k_all, 256, 0);
    if (occ < 1) occ = 1;
    int grid = occ * 256;            // 256 CUs on MI355X
    if (grid > 1024) grid = 1024;    // phase-2 task count ceiling

    void* args[] = {(void*)&h, (void*)&W, (void*)&a, (void*)&src, (void*)&dst,
                    (void*)&Whb, (void*)&s1, (void*)&s2, (void*)&ccount,
                    (void*)&epacked, (void*)&out};
    hipLaunchCooperativeKernel((const void*)k_all, dim3(grid), dim3(256),
                               args, 0, stream);
}

// Round 12
// 284.318 us; speedup vs baseline: 1.1455x; 1.1455x over previous
//
#include <hip/hip_runtime.h>
#include <hip/hip_cooperative_groups.h>
#include <math.h>

namespace cg = cooperative_groups;

#define GN 50000
#define GE 800000
#define INF 128
#define OUTF 64
#define LRELU_ALPHA 0.2f

#define BUCKW   49                          // dsts per bucket
#define NB      1021                        // ceil(50000/49)
#define CAP     1024                        // bucket capacity (mean 783, +8.6 sigma)
#define CHUNK   4096                        // edges per multisplit task
#define NCH     ((GE + CHUNK - 1) / CHUNK)  // 196
#define NGT     782                         // gemm tasks (64 nodes each)
#define NT1     (NGT + NCH)                 // 978 phase-1 tasks

// floor(d/49), exact for d < 50000: 49*85599 = 2^22 + 47; worst-case residue
// 47*1020 + 48*85599 < 2^22.
__device__ __forceinline__ unsigned div49(unsigned d) {
    return (d * 85599u) >> 22;
}

// ---- bf16 helpers (RNE pack, cheap unpack) --------------------------------
__device__ __forceinline__ unsigned short f32_to_bf16(float f) {
    unsigned int u = __float_as_uint(f);
    return (unsigned short)((u + 0x7fffu + ((u >> 16) & 1u)) >> 16);
}
__device__ __forceinline__ float bf16lo(unsigned int u) { return __uint_as_float(u << 16); }
__device__ __forceinline__ float bf16hi(unsigned int u) { return __uint_as_float(u & 0xffff0000u); }

// ---------------------------------------------------------------------------
// Single cooperative kernel (R11 structure, REGISTER CLAMP REMOVED):
//  phase 1: tasks [0,782): GEMM (64 nodes, 4/thread; W in LDS)
//           tasks [782,978): edge multisplit into fixed CAP bucket regions
//                                              -> grid.sync
//  phase 2: one bucket per block: LDS counting sort (49 dsts, 64 bins) +
//           softmax + bf16 Wh gather (8-lane groups, 8 feats/lane, 8-deep
//           unrolled loads) + ELU + coalesced store.
// ccount zeroed by hipMemsetAsync before launch. All phases grid-stride.
// NOTE: no min-waves in launch_bounds -- R11's (256,4) clamped VGPRs to 64
// and spilled the gather working set to scratch (WRITE_SIZE 40 MB, 2.6x).
// ---------------------------------------------------------------------------
__global__ __launch_bounds__(256)
void k_all(const float* __restrict__ h,
           const float* __restrict__ W,
           const float* __restrict__ a,
           const int* __restrict__ src,
           const int* __restrict__ dst,
           unsigned short* __restrict__ Whb,
           float* __restrict__ s1,
           float* __restrict__ s2,
           int* __restrict__ ccount,
           int* __restrict__ epacked,
           float* __restrict__ out) {
    __shared__ __align__(16) unsigned char smem[32768];
    int t = threadIdx.x;
    int grid = gridDim.x;
    cg::grid_group gg = cg::this_grid();

    // ================= phase 1 =================
    for (int task = blockIdx.x; task < NT1; task += grid) {
        if (task < NGT) {
            // ---- GEMM: 64 nodes, 4 nodes/thread (R8 config) ----
            float* Wlds = (float*)smem;  // 32 KB
            for (int i = t * 4; i < INF * OUTF; i += 256 * 4)
                *(float4*)&Wlds[i] = *(const float4*)&W[i];
            __syncthreads();

            int fg = t & 15;
            int ng = t >> 4;
            int jg = fg * 4;
            int n0 = task * 64 + ng * 4;

            int m0 = n0 + 0 < GN ? n0 + 0 : GN - 1;
            int m1 = n0 + 1 < GN ? n0 + 1 : GN - 1;
            int m2 = n0 + 2 < GN ? n0 + 2 : GN - 1;
            int m3 = n0 + 3 < GN ? n0 + 3 : GN - 1;
            const float* h0 = &h[m0 * INF];
            const float* h1 = &h[m1 * INF];
            const float* h2 = &h[m2 * INF];
            const float* h3 = &h[m3 * INF];

            float4 acc0 = {0.f,0.f,0.f,0.f}, acc1 = acc0, acc2 = acc0, acc3 = acc0;
            for (int kc = 0; kc < INF; kc += 4) {
                float4 hv0 = *(const float4*)&h0[kc];
                float4 hv1 = *(const float4*)&h1[kc];
                float4 hv2 = *(const float4*)&h2[kc];
                float4 hv3 = *(const float4*)&h3[kc];
                #pragma unroll
                for (int kk = 0; kk < 4; ++kk) {
                    float4 wv = *(float4*)&Wlds[(kc + kk) * OUTF + jg];
                    float a0 = ((const float*)&hv0)[kk];
                    float a1v = ((const float*)&hv1)[kk];
                    float a2v = ((const float*)&hv2)[kk];
                    float a3 = ((const float*)&hv3)[kk];
                    acc0.x += a0 * wv.x; acc0.y += a0 * wv.y; acc0.z += a0 * wv.z; acc0.w += a0 * wv.w;
                    acc1.x += a1v * wv.x; acc1.y += a1v * wv.y; acc1.z += a1v * wv.z; acc1.w += a1v * wv.w;
                    acc2.x += a2v * wv.x; acc2.y += a2v * wv.y; acc2.z += a2v * wv.z; acc2.w += a2v * wv.w;
                    acc3.x += a3 * wv.x; acc3.y += a3 * wv.y; acc3.z += a3 * wv.z; acc3.w += a3 * wv.w;
                }
            }

            float4 accs[4] = {acc0, acc1, acc2, acc3};
            #pragma unroll
            for (int i = 0; i < 4; ++i) {
                if (n0 + i < GN) {
                    ushort4 p;
                    p.x = f32_to_bf16(accs[i].x); p.y = f32_to_bf16(accs[i].y);
                    p.z = f32_to_bf16(accs[i].z); p.w = f32_to_bf16(accs[i].w);
                    *(ushort4*)&Whb[(n0 + i) * OUTF + jg] = p;
                }
            }

            float4 va1 = *(const float4*)&a[jg];
            float4 va2 = *(const float4*)&a[OUTF + jg];
            float p1[4], p2[4];
            #pragma unroll
            for (int i = 0; i < 4; ++i) {
                p1[i] = accs[i].x * va1.x + accs[i].y * va1.y + accs[i].z * va1.z + accs[i].w * va1.w;
                p2[i] = accs[i].x * va2.x + accs[i].y * va2.y + accs[i].z * va2.z + accs[i].w * va2.w;
            }
            #pragma unroll
            for (int off = 8; off >= 1; off >>= 1) {
                #pragma unroll
                for (int i = 0; i < 4; ++i) {
                    p1[i] += __shfl_down(p1[i], off, 16);
                    p2[i] += __shfl_down(p2[i], off, 16);
                }
            }
            if (fg == 0) {
                #pragma unroll
                for (int i = 0; i < 4; ++i) {
                    if (n0 + i < GN) { s1[n0 + i] = p1[i]; s2[n0 + i] = p2[i]; }
                }
            }
        } else {
            // ---- multisplit: 4096-edge chunk into bucket regions ----
            int* hist = (int*)smem;          // NB ints
            int* run  = hist + NB;           // NB ints (8.2 KB total)
            for (int i = t; i < NB; i += 256) hist[i] = 0;
            __syncthreads();

            int base = (task - NGT) * CHUNK;
            int pk[CHUNK / 256];
            int bb[CHUNK / 256];
            #pragma unroll
            for (int i = 0; i < CHUNK / 256; ++i) {
                int e = base + i * 256 + t;
                if (e < GE) {
                    unsigned d = (unsigned)dst[e];
                    unsigned b = div49(d);
                    pk[i] = (src[e] << 6) | (int)(d - b * BUCKW);
                    bb[i] = (int)b;
                    atomicAdd(&hist[b], 1);
                } else {
                    bb[i] = -1;
                }
            }
            __syncthreads();
            for (int i = t; i < NB; i += 256) {
                int c = hist[i];
                if (c > 0) run[i] = i * CAP + atomicAdd(&ccount[i], c);
            }
            __syncthreads();
            #pragma unroll
            for (int i = 0; i < CHUNK / 256; ++i) {
                if (bb[i] >= 0) {
                    int pos = atomicAdd(&run[bb[i]], 1);
                    epacked[pos] = pk[i];
                }
            }
        }
        __syncthreads();   // protect LDS before next grid-stride task
    }
    __threadfence();       // publish epacked/Whb across XCDs
    gg.sync();

    // ================= phase 2: one bucket per block =================
    int* elds   = (int*)smem;        // 1024
    int* sorted = elds + CAP;        // 1024
    int* hist   = sorted + CAP;      // 64
    int* cur    = hist + 64;         // 64
    int* cstart = cur + 64;          // 66 (65 used)
    float* s2l  = (float*)(cstart + 66);  // 49

    for (int b = blockIdx.x; b < NB; b += grid) {
        int dstbase = b * BUCKW;
        int nd = GN - dstbase;
        if (nd < 0) nd = 0; if (nd > BUCKW) nd = BUCKW;

        int start = b * CAP;
        int cnt = ccount[b];
        if (cnt > CAP) cnt = CAP;    // statistically impossible; safety only

        if (t < 64) hist[t] = 0;
        if (t < BUCKW) s2l[t] = (t < nd) ? s2[dstbase + t] : 0.f;
        __syncthreads();
        for (int i = t; i < cnt; i += 256) {
            int pk = epacked[start + i];
            elds[i] = pk;
            atomicAdd(&hist[pk & 63], 1);
        }
        __syncthreads();
        if (t < 64) {                    // wave 0: inclusive scan of 64 bins
            int v = hist[t];
            int incl = v;
            #pragma unroll
            for (int off = 1; off < 64; off <<= 1) {
                int u = __shfl_up(incl, off, 64);
                if (t >= off) incl += u;
            }
            cstart[t + 1] = incl;
            cur[t] = incl - v;
            if (t == 0) cstart[0] = 0;
        }
        __syncthreads();
        for (int i = t; i < cnt; i += 256) {
            int pk = elds[i];
            int pos = atomicAdd(&cur[pk & 63], 1);
            sorted[pos] = pk;
        }
        __syncthreads();

        int grp  = t >> 3;               // 32 groups of 8 lanes
        int lane = t & 7;
        int jg   = lane * 8;             // 8 feats per lane
        for (int dl = grp; dl < BUCKW; dl += 32) {
            int c0 = cstart[dl], c1 = cstart[dl + 1];
            float acc[8] = {0.f,0.f,0.f,0.f,0.f,0.f,0.f,0.f};
            float den = 0.f;
            float s2n = s2l[dl];
            for (int cb = c0; cb < c1; cb += 8) {
                int my = cb + lane;
                float ex_l = 0.f; int s_l = 0;
                if (my < c1) {
                    int pk = sorted[my];
                    s_l = pk >> 6;
                    float x = s1[s_l] + s2n;
                    x = (x > 0.f) ? x : LRELU_ALPHA * x;
                    ex_l = __expf(x);
                }
                int m = c1 - cb; if (m > 8) m = 8;
                int   sj[8]; float exj[8];
                #pragma unroll
                for (int j = 0; j < 8; ++j) {
                    exj[j] = __shfl(ex_l, j, 8);
                    sj[j]  = __shfl(s_l,  j, 8);
                }
                uint4 wv[8];
                #pragma unroll
                for (int j = 0; j < 8; ++j)
                    if (j < m) wv[j] = *(const uint4*)&Whb[sj[j] * OUTF + jg];
                #pragma unroll
                for (int j = 0; j < 8; ++j) {
                    if (j < m) {
                        float ex = exj[j];
                        den += ex;
                        acc[0] += ex * bf16lo(wv[j].x); acc[1] += ex * bf16hi(wv[j].x);
                        acc[2] += ex * bf16lo(wv[j].y); acc[3] += ex * bf16hi(wv[j].y);
                        acc[4] += ex * bf16lo(wv[j].z); acc[5] += ex * bf16hi(wv[j].z);
                        acc[6] += ex * bf16lo(wv[j].w); acc[7] += ex * bf16hi(wv[j].w);
                    }
                }
            }
            if (dl < nd) {
                float inv = (c1 > c0) ? 1.f / den : 0.f;
                float o[8];
                #pragma unroll
                for (int j = 0; j < 8; ++j) {
                    float v = acc[j] * inv;
                    o[j] = (v > 0.f) ? v : expm1f(v);
                }
                float* op = &out[(dstbase + dl) * OUTF + jg];
                *(float4*)(op + 0) = make_float4(o[0], o[1], o[2], o[3]);
                *(float4*)(op + 4) = make_float4(o[4], o[5], o[6], o[7]);
            }
        }
        __syncthreads();   // protect LDS before next grid-stride bucket
    }
}

extern "C" void kernel_launch(void* const* d_in, const int* in_sizes, int n_in,
                              void* d_out, int out_size, void* d_ws, size_t ws_size,
                              hipStream_t stream) {
    const float* h  = (const float*)d_in[0];
    const int*   ei = (const int*)d_in[1];    // [2, E]: first E = src, next E = dst
    const float* W  = (const float*)d_in[2];
    const float* a  = (const float*)d_in[3];
    const int* src = ei;
    const int* dst = ei + GE;

    float* ws = (float*)d_ws;
    float* s1 = ws;                                          // N
    float* s2 = s1 + GN;                                     // N
    unsigned short* Whb = (unsigned short*)(s2 + GN);        // N*64 bf16
    int* epacked = (int*)(Whb + (size_t)GN * OUTF);          // NB*CAP
    int* ccount  = epacked + (size_t)NB * CAP;               // NB
    float* out = (float*)d_out;

    hipMemsetAsync(ccount, 0, NB * sizeof(int), stream);     // 4 KB, capture-safe

    int occ = 0;
    hipOccupancyMaxActiveBlocksPerMultiprocessor(&occ, (const void*)k_all, 256, 0);
    if (occ < 1) occ = 1;
    int grid = occ * 256;            // 256 CUs on MI355X
    if (grid > 1024) grid = 1024;    // phase-2 task count ceiling

    void* args[] = {(void*)&h, (void*)&W, (void*)&a, (void*)&src, (void*)&dst,
                    (void*)&Whb, (void*)&s1, (void*)&s2, (void*)&ccount,
                    (void*)&epacked, (void*)&out};
    hipLaunchCooperativeKernel((const void*)k_all, dim3(grid), dim3(256),
                               args, 0, stream);
}

// Round 13
// 131.275 us; speedup vs baseline: 2.4809x; 2.1658x over previous
//
#include <hip/hip_runtime.h>
#include <math.h>

#define GN 50000
#define GE 800000
#define INF 128
#define OUTF 64
#define LRELU_ALPHA 0.2f

#define BUCK_SH 6                          // bucket = dst >> 6  (64 dsts/bucket)
#define BUCKW   64
#define NB      ((GN + BUCKW - 1) / BUCKW) // 782 buckets
#define CHUNK   4096                       // edges per mscatter block
#define NCH     ((GE + CHUNK - 1) / CHUNK) // 196 chunks
#define CAP     1536                       // fixed bucket capacity (mean 1023, +16 sigma)

// ---- bf16 helpers (RNE pack, cheap unpack) --------------------------------
__device__ __forceinline__ unsigned short f32_to_bf16(float f) {
    unsigned int u = __float_as_uint(f);
    return (unsigned short)((u + 0x7fffu + ((u >> 16) & 1u)) >> 16);
}
__device__ __forceinline__ float bf16lo(unsigned int u) { return __uint_as_float(u << 16); }
__device__ __forceinline__ float bf16hi(unsigned int u) { return __uint_as_float(u & 0xffff0000u); }

// ---------------------------------------------------------------------------
// K1 "front" (R8 verbatim): blocks [0,NB) GEMM (64 nodes, 4/thread, W in
// LDS); blocks [NB, NB+NCH) edge multisplit into fixed CAP bucket regions.
// Data-independent halves overlap on the CUs. ccount zeroed by memset.
// ---------------------------------------------------------------------------
__global__ __launch_bounds__(256) void k_front(const float* __restrict__ h,
                                               const float* __restrict__ W,
                                               const float* __restrict__ a,
                                               const int* __restrict__ src,
                                               const int* __restrict__ dst,
                                               unsigned short* __restrict__ Whb,
                                               float* __restrict__ s1,
                                               float* __restrict__ s2,
                                               int* __restrict__ ccount,
                                               int* __restrict__ epacked) {
    __shared__ __align__(16) float Wlds[INF * OUTF];  // 32 KB (unioned below)
    int t = threadIdx.x;

    if (blockIdx.x < NB) {
        // ================= GEMM half =================
        for (int i = t * 4; i < INF * OUTF; i += 256 * 4)
            *(float4*)&Wlds[i] = *(const float4*)&W[i];
        __syncthreads();

        int fg = t & 15;           // feature group: 4 feats
        int ng = t >> 4;           // node group: 4 nodes
        int jg = fg * 4;
        int n0 = blockIdx.x * 64 + ng * 4;

        int m0 = n0 + 0 < GN ? n0 + 0 : GN - 1;   // clamp loads; stores guarded
        int m1 = n0 + 1 < GN ? n0 + 1 : GN - 1;
        int m2 = n0 + 2 < GN ? n0 + 2 : GN - 1;
        int m3 = n0 + 3 < GN ? n0 + 3 : GN - 1;
        const float* h0 = &h[m0 * INF];
        const float* h1 = &h[m1 * INF];
        const float* h2 = &h[m2 * INF];
        const float* h3 = &h[m3 * INF];

        float4 acc0 = {0.f,0.f,0.f,0.f}, acc1 = acc0, acc2 = acc0, acc3 = acc0;
        for (int kc = 0; kc < INF; kc += 4) {
            float4 hv0 = *(const float4*)&h0[kc];
            float4 hv1 = *(const float4*)&h1[kc];
            float4 hv2 = *(const float4*)&h2[kc];
            float4 hv3 = *(const float4*)&h3[kc];
            #pragma unroll
            for (int kk = 0; kk < 4; ++kk) {
                float4 wv = *(float4*)&Wlds[(kc + kk) * OUTF + jg];
                float a0 = ((const float*)&hv0)[kk];
                float a1v = ((const float*)&hv1)[kk];
                float a2v = ((const float*)&hv2)[kk];
                float a3 = ((const float*)&hv3)[kk];
                acc0.x += a0 * wv.x; acc0.y += a0 * wv.y; acc0.z += a0 * wv.z; acc0.w += a0 * wv.w;
                acc1.x += a1v * wv.x; acc1.y += a1v * wv.y; acc1.z += a1v * wv.z; acc1.w += a1v * wv.w;
                acc2.x += a2v * wv.x; acc2.y += a2v * wv.y; acc2.z += a2v * wv.z; acc2.w += a2v * wv.w;
                acc3.x += a3 * wv.x; acc3.y += a3 * wv.y; acc3.z += a3 * wv.z; acc3.w += a3 * wv.w;
            }
        }

        float4 accs[4] = {acc0, acc1, acc2, acc3};
        #pragma unroll
        for (int i = 0; i < 4; ++i) {
            if (n0 + i < GN) {
                ushort4 p;
                p.x = f32_to_bf16(accs[i].x); p.y = f32_to_bf16(accs[i].y);
                p.z = f32_to_bf16(accs[i].z); p.w = f32_to_bf16(accs[i].w);
                *(ushort4*)&Whb[(n0 + i) * OUTF + jg] = p;
            }
        }

        float4 va1 = *(const float4*)&a[jg];
        float4 va2 = *(const float4*)&a[OUTF + jg];
        float p1[4], p2[4];
        #pragma unroll
        for (int i = 0; i < 4; ++i) {
            p1[i] = accs[i].x * va1.x + accs[i].y * va1.y + accs[i].z * va1.z + accs[i].w * va1.w;
            p2[i] = accs[i].x * va2.x + accs[i].y * va2.y + accs[i].z * va2.z + accs[i].w * va2.w;
        }
        #pragma unroll
        for (int off = 8; off >= 1; off >>= 1) {
            #pragma unroll
            for (int i = 0; i < 4; ++i) {
                p1[i] += __shfl_down(p1[i], off, 16);
                p2[i] += __shfl_down(p2[i], off, 16);
            }
        }
        if (fg == 0) {
            #pragma unroll
            for (int i = 0; i < 4; ++i) {
                if (n0 + i < GN) { s1[n0 + i] = p1[i]; s2[n0 + i] = p2[i]; }
            }
        }
    } else {
        // ================= multisplit half =================
        int* hist = (int*)Wlds;          // NB ints
        int* run  = hist + NB;           // NB ints
        for (int i = t; i < NB; i += 256) hist[i] = 0;
        __syncthreads();

        int base = (blockIdx.x - NB) * CHUNK;
        int pk[CHUNK / 256];
        int bb[CHUNK / 256];
        #pragma unroll
        for (int i = 0; i < CHUNK / 256; ++i) {
            int e = base + i * 256 + t;
            if (e < GE) {
                int d = dst[e];
                int b = d >> BUCK_SH;
                pk[i] = (src[e] << BUCK_SH) | (d & (BUCKW - 1));
                bb[i] = b;
                atomicAdd(&hist[b], 1);
            } else {
                bb[i] = -1;
            }
        }
        __syncthreads();
        for (int i = t; i < NB; i += 256) {
            int c = hist[i];
            if (c > 0) run[i] = i * CAP + atomicAdd(&ccount[i], c);
        }
        __syncthreads();
        #pragma unroll
        for (int i = 0; i < CHUNK / 256; ++i) {
            if (bb[i] >= 0) {
                int pos = atomicAdd(&run[bb[i]], 1);
                epacked[pos] = pk[i];
            }
        }
    }
}

// ---------------------------------------------------------------------------
// K2: fused sort + softmax + aggregation + ELU, one block per bucket (R8
// shape) with a DEEPER PIPELINE: 16 edges per iteration. Each lane computes
// 2 exp's (2 outstanding s1 gathers), then 16 shfl-broadcast (ex,s) pairs
// and 16 back-to-back uint4 Whb loads before any consume -> one exposed
// latency round per dst instead of two.
// ---------------------------------------------------------------------------
__global__ __launch_bounds__(256) void k_fgather(const int* __restrict__ ccount,
                                                 const int* __restrict__ epacked,
                                                 const float* __restrict__ s1,
                                                 const float* __restrict__ s2,
                                                 const unsigned short* __restrict__ Whb,
                                                 float* __restrict__ out) {
    __shared__ int elds[CAP];
    __shared__ int sorted[CAP];
    __shared__ int hist[BUCKW];
    __shared__ int cur[BUCKW];
    __shared__ int cstart[BUCKW + 1];
    __shared__ float s2l[BUCKW];

    int t = threadIdx.x;
    int b = blockIdx.x;
    int dstbase = b * BUCKW;
    int nd = GN - dstbase; if (nd > BUCKW) nd = BUCKW;

    int start = b * CAP;
    int cnt   = ccount[b];
    if (cnt > CAP) cnt = CAP;           // statistically impossible; safety only

    if (t < BUCKW) {
        hist[t] = 0;
        s2l[t] = (t < nd) ? s2[dstbase + t] : 0.f;
    }
    __syncthreads();
    for (int i = t; i < cnt; i += 256) {
        int pk = epacked[start + i];
        elds[i] = pk;
        atomicAdd(&hist[pk & (BUCKW - 1)], 1);
    }
    __syncthreads();
    if (t < 64) {                        // wave 0: inclusive scan of 64 bins
        int v = hist[t];
        int incl = v;
        #pragma unroll
        for (int off = 1; off < 64; off <<= 1) {
            int u = __shfl_up(incl, off, 64);
            if (t >= off) incl += u;
        }
        cstart[t + 1] = incl;
        cur[t] = incl - v;
        if (t == 0) cstart[0] = 0;
    }
    __syncthreads();
    for (int i = t; i < cnt; i += 256) {
        int pk = elds[i];
        int pos = atomicAdd(&cur[pk & (BUCKW - 1)], 1);
        sorted[pos] = pk;
    }
    __syncthreads();

    int grp  = t >> 3;                   // 32 groups of 8 lanes
    int lane = t & 7;
    int jg   = lane * 8;                 // 8 feats per lane
    for (int dl = grp; dl < BUCKW; dl += 32) {
        int c0 = cstart[dl], c1 = cstart[dl + 1];
        float acc[8] = {0.f,0.f,0.f,0.f,0.f,0.f,0.f,0.f};
        float den = 0.f;
        float s2n = s2l[dl];
        for (int cb = c0; cb < c1; cb += 16) {
            int my0 = cb + lane;
            int my1 = cb + 8 + lane;
            float exA = 0.f, exB = 0.f;
            int sA = 0, sB = 0;
            if (my0 < c1) sA = sorted[my0] >> BUCK_SH;
            if (my1 < c1) sB = sorted[my1] >> BUCK_SH;
            // two outstanding s1 gathers per lane
            float xA = 0.f, xB = 0.f;
            if (my0 < c1) xA = s1[sA] + s2n;
            if (my1 < c1) xB = s1[sB] + s2n;
            if (my0 < c1) {
                xA = (xA > 0.f) ? xA : LRELU_ALPHA * xA;
                exA = __expf(xA);
            }
            if (my1 < c1) {
                xB = (xB > 0.f) ? xB : LRELU_ALPHA * xB;
                exB = __expf(xB);
            }
            int m = c1 - cb; if (m > 16) m = 16;
            int   sj[16]; float exj[16];
            #pragma unroll
            for (int j = 0; j < 8; ++j) {
                exj[j]     = __shfl(exA, j, 8);
                sj[j]      = __shfl(sA,  j, 8);
                exj[j + 8] = __shfl(exB, j, 8);
                sj[j + 8]  = __shfl(sB,  j, 8);
            }
            uint4 wv[16];
            #pragma unroll
            for (int j = 0; j < 16; ++j)
                if (j < m) wv[j] = *(const uint4*)&Whb[sj[j] * OUTF + jg];
            #pragma unroll
            for (int j = 0; j < 16; ++j) {
                if (j < m) {
                    float ex = exj[j];
                    den += ex;
                    acc[0] += ex * bf16lo(wv[j].x); acc[1] += ex * bf16hi(wv[j].x);
                    acc[2] += ex * bf16lo(wv[j].y); acc[3] += ex * bf16hi(wv[j].y);
                    acc[4] += ex * bf16lo(wv[j].z); acc[5] += ex * bf16hi(wv[j].z);
                    acc[6] += ex * bf16lo(wv[j].w); acc[7] += ex * bf16hi(wv[j].w);
                }
            }
        }
        if (dl < nd) {
            float inv = (c1 > c0) ? 1.f / den : 0.f;
            float o[8];
            #pragma unroll
            for (int j = 0; j < 8; ++j) {
                float v = acc[j] * inv;
                o[j] = (v > 0.f) ? v : expm1f(v);
            }
            float* op = &out[(dstbase + dl) * OUTF + jg];
            *(float4*)(op + 0) = make_float4(o[0], o[1], o[2], o[3]);
            *(float4*)(op + 4) = make_float4(o[4], o[5], o[6], o[7]);
        }
    }
}

extern "C" void kernel_launch(void* const* d_in, const int* in_sizes, int n_in,
                              void* d_out, int out_size, void* d_ws, size_t ws_size,
                              hipStream_t stream) {
    const float* h  = (const float*)d_in[0];
    const int*   ei = (const int*)d_in[1];    // [2, E]: first E = src, next E = dst
    const float* W  = (const float*)d_in[2];
    const float* a  = (const float*)d_in[3];
    const int* src = ei;
    const int* dst = ei + GE;

    float* ws = (float*)d_ws;
    float* s1 = ws;                                          // N
    float* s2 = s1 + GN;                                     // N
    unsigned short* Whb = (unsigned short*)(s2 + GN);        // N*64 bf16
    int* epacked = (int*)(Whb + (size_t)GN * OUTF);          // NB*CAP
    int* ccount  = epacked + (size_t)NB * CAP;               // NB
    float* out = (float*)d_out;

    hipMemsetAsync(ccount, 0, NB * sizeof(int), stream);     // 3 KB, capture-safe
    k_front<<<NB + NCH, 256, 0, stream>>>(h, W, a, src, dst, Whb, s1, s2,
                                          ccount, epacked);
    k_fgather<<<NB, 256, 0, stream>>>(ccount, epacked, s1, s2, Whb, out);
}